// Round 1
// baseline (2790.763 us; speedup 1.0000x reference)
//
#include <hip/hip_runtime.h>

// RealISTFT: frames = [S_real | S_imag] @ [cos_b | -sin_b]^T  (M=64000, N=1024, K=1026)
// then windowed overlap-add (each frame sample hits exactly ONE output sample),
// then analytic win_env normalization + trim.

#define NFFT   1024
#define NFREQ  513
#define KDIM   1026      // 2*NFREQ
#define TFR    4000
#define NB     16
#define HOP    256
#define OUTLEN 1023744   // (TFR-1)*HOP
#define STRIM  512

#define BM 64
#define BN 64
#define BK 16

// ---- kernel 1: basis table bas[k][n], k<513: cos, k>=513: -sin (sign folded) ----
__global__ void build_basis(float* __restrict__ bas) {
    const int k = blockIdx.x;                       // 0..1025
    const int f = (k < NFREQ) ? k : (k - NFREQ);
    const float scale = (f == 0 || f == NFFT / 2) ? (1.0f / NFFT) : (2.0f / NFFT);
    const float step = 6.28318530717958647692f / (float)NFFT;
    for (int n = threadIdx.x; n < NFFT; n += blockDim.x) {
        const int m = (n * f) & (NFFT - 1);          // exact period-1024 range reduction
        const float ang = step * (float)m;
        const float v = (k < NFREQ) ? (cosf(ang) * scale) : (-sinf(ang) * scale);
        bas[(size_t)k * NFFT + n] = v;
    }
}

// ---- kernel 2: tiled fp32 GEMM + windowed OLA scatter (atomicAdd) ----
__global__ __launch_bounds__(256, 4) void gemm_ola(
        const float* __restrict__ mag, const float* __restrict__ cosp,
        const float* __restrict__ sinp, const float* __restrict__ bas,
        const float* __restrict__ window, float* __restrict__ out) {
    const int b  = blockIdx.z;
    const int t0 = blockIdx.y * BM;
    const int n0 = blockIdx.x * BN;

    __shared__ float As[BK][BM];
    __shared__ float Bs[BK][BN];

    const int tid = threadIdx.x;
    const int lm  = tid & 63;       // load lane: consecutive t / consecutive n
    const int lk  = tid >> 6;       // wave id 0..3 -> k-row (wave-uniform branch below)
    const int tx  = tid & 15;
    const int ty  = tid >> 4;

    const size_t bstride = (size_t)NFREQ * TFR;
    const float* magB = mag  + (size_t)b * bstride;
    const float* cosB = cosp + (size_t)b * bstride;
    const float* sinB = sinp + (size_t)b * bstride;

    const int t = t0 + lm;
    const bool tvalid = (t < TFR);

    float acc[4][4] = {};

    for (int k0 = 0; k0 < KDIM; k0 += BK) {
        #pragma unroll
        for (int u = 0; u < BK / 4; ++u) {
            const int kk = lk + u * 4;
            const int k  = k0 + kk;
            float av = 0.0f;
            if (k < KDIM && tvalid) {
                if (k < NFREQ) {                     // S_real = mag*cos_phase
                    const size_t idx = (size_t)k * TFR + t;
                    av = magB[idx] * cosB[idx];
                } else {                             // S_imag = mag*sin_phase (sign in basis)
                    const size_t idx = (size_t)(k - NFREQ) * TFR + t;
                    av = magB[idx] * sinB[idx];
                }
            }
            As[kk][lm] = av;
            float bv = 0.0f;
            if (k < KDIM) bv = bas[(size_t)k * NFFT + (n0 + lm)];
            Bs[kk][lm] = bv;
        }
        __syncthreads();
        #pragma unroll
        for (int kk = 0; kk < BK; ++kk) {
            const float4 a4 = *(const float4*)&As[kk][ty * 4];
            const float4 b4 = *(const float4*)&Bs[kk][tx * 4];
            const float a[4]  = {a4.x, a4.y, a4.z, a4.w};
            const float bb[4] = {b4.x, b4.y, b4.z, b4.w};
            #pragma unroll
            for (int i = 0; i < 4; ++i)
                #pragma unroll
                for (int j = 0; j < 4; ++j)
                    acc[i][j] = fmaf(a[i], bb[j], acc[i][j]);
        }
        __syncthreads();
    }

    // Epilogue: frames[t][n]*window[n] -> audio[s = t*HOP + n], trimmed by STRIM.
    float* outB = out + (size_t)b * OUTLEN;
    #pragma unroll
    for (int i = 0; i < 4; ++i) {
        const int tt = t0 + ty * 4 + i;
        if (tt < TFR) {
            #pragma unroll
            for (int j = 0; j < 4; ++j) {
                const int n = n0 + tx * 4 + j;
                const float v = acc[i][j] * window[n];
                const int o = tt * HOP + n - STRIM;
                if (o >= 0 && o < OUTLEN) atomicAdd(&outB[o], v);
            }
        }
    }
}

// ---- kernel 3: divide by analytic win_env (sum of <=4 overlapping window^2) ----
__global__ void normalize_k(const float* __restrict__ window, float* __restrict__ out) {
    const int b = blockIdx.y;
    const int o = blockIdx.x * 256 + threadIdx.x;   // OUTLEN % 256 == 0
    const int s = o + STRIM;
    const int j = s & (HOP - 1);
    const int th = s >> 8;
    float env = 0.0f;
    #pragma unroll
    for (int k = 0; k < 4; ++k) {
        const int tt = th - k;
        if (tt >= 0 && tt < TFR) {
            const float w = window[j + k * HOP];
            env += w * w;
        }
    }
    out[(size_t)b * OUTLEN + o] /= (env + 1e-11f);
}

extern "C" void kernel_launch(void* const* d_in, const int* in_sizes, int n_in,
                              void* d_out, int out_size, void* d_ws, size_t ws_size,
                              hipStream_t stream) {
    const float* mag    = (const float*)d_in[0];
    const float* cosp   = (const float*)d_in[1];
    const float* sinp   = (const float*)d_in[2];
    const float* window = (const float*)d_in[3];
    float* out = (float*)d_out;
    float* bas = (float*)d_ws;                      // KDIM*NFFT floats = 4.2 MB

    hipMemsetAsync(d_out, 0, (size_t)out_size * sizeof(float), stream);
    build_basis<<<KDIM, 256, 0, stream>>>(bas);
    gemm_ola<<<dim3(NFFT / BN, (TFR + BM - 1) / BM, NB), 256, 0, stream>>>(
        mag, cosp, sinp, bas, window, out);
    normalize_k<<<dim3(OUTLEN / 256, NB), 256, 0, stream>>>(window, out);
}

// Round 2
// 860.460 us; speedup vs baseline: 3.2433x; 3.2433x over previous
//
#include <hip/hip_runtime.h>
#include <hip/hip_bf16.h>

// RealISTFT = bf16 MFMA GEMM (m97 structure) + fused windowed OLA + analytic env norm.
// frames[b,t,n] = sum_k S[b,t,k] * bas[n,k]   (both k-contiguous bf16)
//   S cols: [0,513) = mag*cos_phase, [544,1057) = mag*sin_phase, rest 0
//   bas cols: [0,513) = cos(2pi n f/1024)*scale, [544,1057) = -sin(...)*scale, rest 0

#define NFFT   1024
#define NFREQ  513
#define TFR    4000
#define NB     16
#define HOP    256
#define OUTLEN 1023744   // (TFR-1)*HOP
#define STRIM  512
#define KPAD   1088      // 34*32 ; imag section base 544 (=17*32)
#define IMB    544
#define TPAD   4096

typedef __bf16 bf16x8 __attribute__((ext_vector_type(8)));
typedef float  f32x4  __attribute__((ext_vector_type(4)));
typedef unsigned short ushort8 __attribute__((ext_vector_type(8)));

__device__ inline unsigned short f2bf(float x) {
    unsigned u = __float_as_uint(x);
    unsigned r = (u + 0x7FFFu + ((u >> 16) & 1u)) >> 16;   // RTN-even
    return (unsigned short)r;
}

// ---- kernel 1: S[b][t][k] bf16, transposed from [k][t] fp32 inputs ----
// grid: (17 f-tiles, TPAD/64 t-tiles, NB). Each block: f in [f0,f0+32), t in [t0,t0+64).
__global__ __launch_bounds__(256) void prep_s(
        const float* __restrict__ mag, const float* __restrict__ cosp,
        const float* __restrict__ sinp, unsigned short* __restrict__ S) {
    const int f0 = blockIdx.x * 32, t0 = blockIdx.y * 64, b = blockIdx.z;
    __shared__ float Lr[32][65];
    __shared__ float Li[32][65];
    const int tid = threadIdx.x;
    const int tt = tid & 63, kq = tid >> 6;
    const size_t bst = (size_t)NFREQ * TFR;
    const float* magB = mag  + (size_t)b * bst;
    const float* cosB = cosp + (size_t)b * bst;
    const float* sinB = sinp + (size_t)b * bst;
    const int t = t0 + tt;
    #pragma unroll
    for (int u = 0; u < 8; ++u) {
        const int kk = kq * 8 + u;
        const int f = f0 + kk;
        float vr = 0.f, vi = 0.f;
        if (f < NFREQ && t < TFR) {
            const size_t i = (size_t)f * TFR + t;
            const float m = magB[i];
            vr = m * cosB[i];
            vi = m * sinB[i];
        }
        Lr[kk][tt] = vr;
        Li[kk][tt] = vi;
    }
    __syncthreads();
    const int tt2 = tid >> 2, kk0 = (tid & 3) * 8;
    ushort8 pr, pi;
    #pragma unroll
    for (int j = 0; j < 8; ++j) {
        pr[j] = f2bf(Lr[kk0 + j][tt2]);
        pi[j] = f2bf(Li[kk0 + j][tt2]);
    }
    unsigned short* rowp = S + ((size_t)b * TPAD + t0 + tt2) * KPAD;
    *(ushort8*)(rowp + f0 + kk0)       = pr;
    *(ushort8*)(rowp + IMB + f0 + kk0) = pi;
}

// ---- kernel 2: transposed basis bas[n][k] bf16 ----
__global__ void build_basis_t(unsigned short* __restrict__ bas) {
    const int n = blockIdx.x;                        // 0..1023
    const float step = 6.28318530717958647692f / (float)NFFT;
    for (int k = threadIdx.x; k < KPAD; k += 256) {
        float v = 0.f;
        if (k < NFREQ) {
            const int f = k;
            const float scale = (f == 0 || f == NFFT / 2) ? (1.f / NFFT) : (2.f / NFFT);
            v = cosf(step * (float)((n * f) & (NFFT - 1))) * scale;
        } else if (k >= IMB && k < IMB + NFREQ) {
            const int f = k - IMB;
            const float scale = (f == 0 || f == NFFT / 2) ? (1.f / NFFT) : (2.f / NFFT);
            v = -sinf(step * (float)((n * f) & (NFFT - 1))) * scale;
        }
        bas[(size_t)n * KPAD + k] = f2bf(v);
    }
}

// ---- kernel 3: 128x128 bf16 MFMA GEMM + windowed OLA scatter ----
__global__ __launch_bounds__(256) void gemm_ola(
        const unsigned short* __restrict__ S, const unsigned short* __restrict__ bas,
        const float* __restrict__ window, float* __restrict__ out) {
    const int b = blockIdx.z, t0 = blockIdx.y * 128, n0 = blockIdx.x * 128;
    __shared__ unsigned short As[128 * 32];
    __shared__ unsigned short Bs[128 * 32];
    const int tid = threadIdx.x;
    const int lane = tid & 63, wave = tid >> 6;
    const int wr = wave >> 1, wc = wave & 1;
    const int quad = lane >> 4, r16 = lane & 15;

    const unsigned short* Sb = S + (size_t)b * TPAD * KPAD;

    f32x4 acc[4][4];
    #pragma unroll
    for (int mi = 0; mi < 4; ++mi)
        #pragma unroll
        for (int ni = 0; ni < 4; ++ni)
            acc[mi][ni] = 0.f;

    const int ldrow = (lane >> 2);          // 0..15 within chunk
    const int ko    = (lane & 3) * 8;       // bf16 offset within 64B row

    for (int k0 = 0; k0 < KPAD; k0 += 32) {
        #pragma unroll
        for (int i = 0; i < 2; ++i) {
            const int chunk = wave * 2 + i;          // 0..7
            const int row = chunk * 16 + ldrow;      // 0..127
            const unsigned short* ga = Sb + (size_t)(t0 + row) * KPAD + k0 + ko;
            __builtin_amdgcn_global_load_lds(
                (const __attribute__((address_space(1))) void*)ga,
                (__attribute__((address_space(3))) void*)(As + chunk * 512 + lane * 8),
                16, 0, 0);
            const unsigned short* gb = bas + (size_t)(n0 + row) * KPAD + k0 + ko;
            __builtin_amdgcn_global_load_lds(
                (const __attribute__((address_space(1))) void*)gb,
                (__attribute__((address_space(3))) void*)(Bs + chunk * 512 + lane * 8),
                16, 0, 0);
        }
        __syncthreads();
        bf16x8 af[4], bfr[4];
        #pragma unroll
        for (int mi = 0; mi < 4; ++mi)
            af[mi] = *(const bf16x8*)(As + (wr * 64 + mi * 16 + r16) * 32 + quad * 8);
        #pragma unroll
        for (int ni = 0; ni < 4; ++ni)
            bfr[ni] = *(const bf16x8*)(Bs + (wc * 64 + ni * 16 + r16) * 32 + quad * 8);
        #pragma unroll
        for (int mi = 0; mi < 4; ++mi)
            #pragma unroll
            for (int ni = 0; ni < 4; ++ni)
                acc[mi][ni] = __builtin_amdgcn_mfma_f32_16x16x32_bf16(
                    af[mi], bfr[ni], acc[mi][ni], 0, 0, 0);
        __syncthreads();
    }

    // Epilogue: v = acc * window[n]; out[t*HOP + n - STRIM] += v (exactly-one-target OLA).
    float* outB = out + (size_t)b * OUTLEN;
    #pragma unroll
    for (int ni = 0; ni < 4; ++ni) {
        const int n = n0 + wc * 64 + ni * 16 + r16;
        const float w = window[n];
        #pragma unroll
        for (int mi = 0; mi < 4; ++mi) {
            #pragma unroll
            for (int reg = 0; reg < 4; ++reg) {
                const int t = t0 + wr * 64 + mi * 16 + quad * 4 + reg;
                if (t < TFR) {
                    const int o = t * HOP + n - STRIM;
                    if (o >= 0 && o < OUTLEN)
                        atomicAdd(&outB[o], acc[mi][ni][reg] * w);
                }
            }
        }
    }
}

// ---- kernel 4: divide by analytic win_env ----
__global__ void normalize_k(const float* __restrict__ window, float* __restrict__ out) {
    const int b = blockIdx.y;
    const int o = blockIdx.x * 256 + threadIdx.x;   // OUTLEN % 256 == 0
    const int s = o + STRIM;
    const int j = s & (HOP - 1);
    const int th = s >> 8;
    float env = 0.f;
    #pragma unroll
    for (int k = 0; k < 4; ++k) {
        const int tt = th - k;
        if (tt >= 0 && tt < TFR) {
            const float w = window[j + k * HOP];
            env += w * w;
        }
    }
    out[(size_t)b * OUTLEN + o] /= (env + 1e-11f);
}

extern "C" void kernel_launch(void* const* d_in, const int* in_sizes, int n_in,
                              void* d_out, int out_size, void* d_ws, size_t ws_size,
                              hipStream_t stream) {
    const float* mag    = (const float*)d_in[0];
    const float* cosp   = (const float*)d_in[1];
    const float* sinp   = (const float*)d_in[2];
    const float* window = (const float*)d_in[3];
    float* out = (float*)d_out;

    unsigned short* S   = (unsigned short*)d_ws;                       // 16*4096*1088*2 B
    unsigned short* bas = S + (size_t)NB * TPAD * KPAD;                // 1024*1088*2 B

    hipMemsetAsync(d_out, 0, (size_t)out_size * sizeof(float), stream);
    prep_s<<<dim3(17, TPAD / 64, NB), 256, 0, stream>>>(mag, cosp, sinp, S);
    build_basis_t<<<NFFT, 256, 0, stream>>>(bas);
    gemm_ola<<<dim3(NFFT / 128, 32, NB), 256, 0, stream>>>(S, bas, window, out);
    normalize_k<<<dim3(OUTLEN / 256, NB), 256, 0, stream>>>(window, out);
}